// Round 1
// baseline (79.716 us; speedup 1.0000x reference)
//
#include <hip/hip_runtime.h>

// DimeNet Bessel radial basis with smooth cutoff envelope.
// out[e][k] = env(d/c) * sin(freq[k] * d/c),  d = |R[idx_i[e]] - R[idx_j[e]]|
// env(x) = 1/x + a*x^5 + b*x^6 + c*x^7, p=6: a=-28, b=48, c=-21

#define NUM_RADIAL 16
constexpr float INV_CUTOFF = 1.0f / 5.0f;

__global__ __launch_bounds__(256) void dimenet_rbf_kernel(
    const float* __restrict__ R,
    const float* __restrict__ freq,
    const int* __restrict__ idx_i,
    const int* __restrict__ idx_j,
    float* __restrict__ out,
    int nE)
{
    int e = blockIdx.x * blockDim.x + threadIdx.x;
    if (e >= nE) return;

    int i = idx_i[e];
    int j = idx_j[e];

    // R rows are 12 B each -> 3 scalar loads per endpoint; L2-resident (1.2 MB)
    float xi = R[3 * i + 0], yi = R[3 * i + 1], zi = R[3 * i + 2];
    float xj = R[3 * j + 0], yj = R[3 * j + 1], zj = R[3 * j + 2];

    float dx = xi - xj;
    float dy = yi - yj;
    float dz = zi - zj;
    float d2 = dx * dx + dy * dy + dz * dz;
    float d  = sqrtf(fmaxf(d2, 0.0f));

    float x = d * INV_CUTOFF;

    // envelope: 1/x + x^5 * (a + b*x + c*x^2), a=-28, b=48, c=-21
    float x2 = x * x;
    float x5 = x2 * x2 * x;
    float poly = -28.0f + x * (48.0f + x * (-21.0f));
    float env = 1.0f / x + x5 * poly;

    // 16 radial basis values, written as 4x float4 (row is 64B aligned)
    float4* orow = reinterpret_cast<float4*>(out + (size_t)e * NUM_RADIAL);

#pragma unroll
    for (int q = 0; q < 4; ++q) {
        float4 v;
        v.x = env * __sinf(freq[4 * q + 0] * x);
        v.y = env * __sinf(freq[4 * q + 1] * x);
        v.z = env * __sinf(freq[4 * q + 2] * x);
        v.w = env * __sinf(freq[4 * q + 3] * x);
        orow[q] = v;
    }
}

extern "C" void kernel_launch(void* const* d_in, const int* in_sizes, int n_in,
                              void* d_out, int out_size, void* d_ws, size_t ws_size,
                              hipStream_t stream)
{
    const float* R     = (const float*)d_in[0];
    const float* freq  = (const float*)d_in[1];
    const int*   idx_i = (const int*)d_in[2];
    const int*   idx_j = (const int*)d_in[3];
    float* out = (float*)d_out;

    int nE = in_sizes[2];

    int block = 256;
    int grid = (nE + block - 1) / block;
    dimenet_rbf_kernel<<<grid, block, 0, stream>>>(R, freq, idx_i, idx_j, out, nE);
}

// Round 2
// 47.411 us; speedup vs baseline: 1.6814x; 1.6814x over previous
//
#include <hip/hip_runtime.h>

// DimeNet Bessel radial basis with smooth cutoff envelope.
// out[e][k] = env(d/c) * sin(freq[k] * d/c),  d = |R[idx_i[e]] - R[idx_j[e]]|
// env(x) = 1/x + a*x^5 + b*x^6 + c*x^7, p=6: a=-28, b=48, c=-21
//
// 4 threads per edge: thread computes d redundantly (cheap, cache-hit gathers)
// and writes ONE float4 (its quarter of the 16-wide rbf row). Lanes in a wave
// then store at contiguous 16B stride -> fully coalesced 64B-line writes,
// vs. the 1-thread/edge layout where each store instruction scattered 16B
// into 64 distinct lines.

#define NUM_RADIAL 16
constexpr float INV_CUTOFF = 1.0f / 5.0f;

__global__ __launch_bounds__(256) void dimenet_rbf_kernel(
    const float* __restrict__ R,
    const float* __restrict__ freq,
    const int* __restrict__ idx_i,
    const int* __restrict__ idx_j,
    float* __restrict__ out,
    int nE)
{
    int tid = blockIdx.x * blockDim.x + threadIdx.x;
    int e = tid >> 2;       // edge index
    int q = tid & 3;        // which float4 quarter of the 16-wide row
    if (e >= nE) return;

    int i = idx_i[e];
    int j = idx_j[e];

    // R rows are 12 B each; random access but R is 1.2 MB -> L1/L2 resident.
    float xi = R[3 * i + 0], yi = R[3 * i + 1], zi = R[3 * i + 2];
    float xj = R[3 * j + 0], yj = R[3 * j + 1], zj = R[3 * j + 2];

    float dx = xi - xj;
    float dy = yi - yj;
    float dz = zi - zj;
    float d2 = dx * dx + dy * dy + dz * dz;
    float d  = sqrtf(fmaxf(d2, 0.0f));

    float x = d * INV_CUTOFF;

    // envelope: 1/x + x^5 * (a + b*x + c*x^2), a=-28, b=48, c=-21
    float x2 = x * x;
    float x5 = x2 * x2 * x;
    float poly = -28.0f + x * (48.0f + x * (-21.0f));
    float env = __builtin_amdgcn_rcpf(x) + x5 * poly;

    // this thread's 4 radial basis values
    float f0 = freq[4 * q + 0];
    float f1 = freq[4 * q + 1];
    float f2 = freq[4 * q + 2];
    float f3 = freq[4 * q + 3];

    float4 v;
    v.x = env * __sinf(f0 * x);
    v.y = env * __sinf(f1 * x);
    v.z = env * __sinf(f2 * x);
    v.w = env * __sinf(f3 * x);

    // contiguous across lanes: thread tid writes out[tid*4 .. tid*4+3]
    reinterpret_cast<float4*>(out)[tid] = v;
}

extern "C" void kernel_launch(void* const* d_in, const int* in_sizes, int n_in,
                              void* d_out, int out_size, void* d_ws, size_t ws_size,
                              hipStream_t stream)
{
    const float* R     = (const float*)d_in[0];
    const float* freq  = (const float*)d_in[1];
    const int*   idx_i = (const int*)d_in[2];
    const int*   idx_j = (const int*)d_in[3];
    float* out = (float*)d_out;

    int nE = in_sizes[2];

    int block = 256;
    long long nthreads = 4LL * nE;
    int grid = (int)((nthreads + block - 1) / block);
    dimenet_rbf_kernel<<<grid, block, 0, stream>>>(R, freq, idx_i, idx_j, out, nE);
}